// Round 1
// baseline (367.736 us; speedup 1.0000x reference)
//
#include <hip/hip_runtime.h>

// SelfAttention: x(4,2048,1024) fp32; Linear y = x @ W^T + b for Q,K,V;
// S = QK^T/32; P = softmax(S); O = P V; out = O @ Wo^T + bo.
// Strategy: bf16 MFMA (16x16x32) m97-style gemm_bt everywhere.
// Workspace layout (136 MB total, aliased by lifetime):
//   [0,16)MB    x_bf16  -> later O (attn output, bf16)
//   [16,24)MB   wq,wk,wv,wo bf16 (2MB each)
//   [24,40)MB   Q bf16  -> later P (first half)
//   [40,56)MB   K bf16  -> later P (second half)   (P = [24,56) = 32MB)
//   [56,72)MB   VT bf16 (V transposed, [4][1024][2048])
//   [72,88)MB   V bf16  -> dead after transpose; S fp32 = [72,136) (64MB)

typedef __bf16 bf16x8 __attribute__((ext_vector_type(8)));
typedef float f32x4 __attribute__((ext_vector_type(4)));

__device__ __forceinline__ unsigned short f32_to_bf16(float f) {
  unsigned int u = __float_as_uint(f);
  u += 0x7fffu + ((u >> 16) & 1u);   // round-to-nearest-even
  return (unsigned short)(u >> 16);
}

__device__ __forceinline__ void load_lds16(const void* g, void* l) {
  __builtin_amdgcn_global_load_lds(
      (const __attribute__((address_space(1))) void*)g,
      (__attribute__((address_space(3))) void*)l, 16, 0, 0);
}

// ---------------------------------------------------------------- cast kernel
__global__ __launch_bounds__(256) void cast_f32_bf16(
    const float4* __restrict__ in, ushort4* __restrict__ out, int n4) {
  int i = blockIdx.x * 256 + threadIdx.x;
  if (i < n4) {
    float4 f = in[i];
    ushort4 u;
    u.x = f32_to_bf16(f.x);
    u.y = f32_to_bf16(f.y);
    u.z = f32_to_bf16(f.z);
    u.w = f32_to_bf16(f.w);
    out[i] = u;
  }
}

// ------------------------------------------------------------ gemm (B^T form)
// C[b][M][N] = alpha * A[b][M][K] * B[b][N][K]^T + bias[N]
// A,B bf16 (as ushort); C fp32 or bf16 per out_bf16 flag.
// Tile 128x128, BK=64, 256 threads = 4 waves in 2x2, each wave 64x64 = 4x4
// MFMA 16x16x32 accumulators. Staging via global_load_lds dwordx4 (m97).
__global__ __launch_bounds__(256) void gemm_bt(
    const unsigned short* __restrict__ A, const unsigned short* __restrict__ B,
    void* __restrict__ C, const float* __restrict__ bias,
    int M, int N, int K, float alpha, int out_bf16,
    long long sA, long long sB, long long sC) {
  __shared__ unsigned short As[128 * 64];
  __shared__ unsigned short Bs[128 * 64];

  const int bz = blockIdx.z;
  A += (long long)bz * sA;
  B += (long long)bz * sB;

  const int bm = blockIdx.y, bn = blockIdx.x;
  const int tid = threadIdx.x;
  const int lane = tid & 63, wave = tid >> 6;
  const int wr = wave >> 1, wc = wave & 1;
  const int l16 = lane & 15, quad = lane >> 4;

  f32x4 acc[4][4] = {};

  // staging map: thread t covers global row (t>>3)+32r, 8 bf16 at col (t&7)*8
  const int srow = tid >> 3;
  const int scol = (tid & 7) * 8;
  const unsigned short* gA = A + (long long)(bm * 128 + srow) * K + scol;
  const unsigned short* gB = B + (long long)(bn * 128 + srow) * K + scol;
  char* ldsA = (char*)As + wave * 1024;  // wave-uniform base; HW adds lane*16
  char* ldsB = (char*)Bs + wave * 1024;

  for (int k0 = 0; k0 < K; k0 += 64) {
#pragma unroll
    for (int r = 0; r < 4; r++)
      load_lds16(gA + k0 + (long long)r * 32 * K, ldsA + r * 4096);
#pragma unroll
    for (int r = 0; r < 4; r++)
      load_lds16(gB + k0 + (long long)r * 32 * K, ldsB + r * 4096);
    __syncthreads();  // drains vmcnt: LDS tiles ready

#pragma unroll
    for (int kk = 0; kk < 64; kk += 32) {
      bf16x8 af[4], bf[4];
      const int ko = kk + quad * 8;
#pragma unroll
      for (int mi = 0; mi < 4; mi++)
        af[mi] = *(const bf16x8*)(As + (wr * 64 + mi * 16 + l16) * 64 + ko);
#pragma unroll
      for (int ni = 0; ni < 4; ni++)
        bf[ni] = *(const bf16x8*)(Bs + (wc * 64 + ni * 16 + l16) * 64 + ko);
#pragma unroll
      for (int mi = 0; mi < 4; mi++)
#pragma unroll
        for (int ni = 0; ni < 4; ni++)
          acc[mi][ni] = __builtin_amdgcn_mfma_f32_16x16x32_bf16(
              af[mi], bf[ni], acc[mi][ni], 0, 0, 0);
    }
    __syncthreads();  // protect LDS before next stage overwrites
  }

  // epilogue: D element (row = quad*4+reg, col = l16) within each 16x16 tile
  const int orow0 = bm * 128 + wr * 64 + quad * 4;
  const int ocol0 = bn * 128 + wc * 64 + l16;
  if (out_bf16) {
    unsigned short* Cp = (unsigned short*)C + (long long)bz * sC;
#pragma unroll
    for (int mi = 0; mi < 4; mi++)
#pragma unroll
      for (int ni = 0; ni < 4; ni++) {
        const int col = ocol0 + ni * 16;
        const float bv = bias ? bias[col] : 0.f;
#pragma unroll
        for (int r = 0; r < 4; r++) {
          const float o = acc[mi][ni][r] * alpha + bv;
          Cp[(long long)(orow0 + mi * 16 + r) * N + col] = f32_to_bf16(o);
        }
      }
  } else {
    float* Cp = (float*)C + (long long)bz * sC;
#pragma unroll
    for (int mi = 0; mi < 4; mi++)
#pragma unroll
      for (int ni = 0; ni < 4; ni++) {
        const int col = ocol0 + ni * 16;
        const float bv = bias ? bias[col] : 0.f;
#pragma unroll
        for (int r = 0; r < 4; r++) {
          const float o = acc[mi][ni][r] * alpha + bv;
          Cp[(long long)(orow0 + mi * 16 + r) * N + col] = o;
        }
      }
  }
}

// ------------------------------------------------------- V transpose (bf16)
// V: [4*2048][1024] -> VT: [4][1024][2048]
__global__ __launch_bounds__(256) void transpose_v(
    const unsigned short* __restrict__ V, unsigned short* __restrict__ VT) {
  __shared__ unsigned short tile[64][65];
  const int d0 = blockIdx.x * 64, s0 = blockIdx.y * 64, b = blockIdx.z;
  const int t = threadIdx.x;
  const unsigned short* src = V + ((long long)b * 2048 + s0) * 1024 + d0;
#pragma unroll
  for (int i = 0; i < 16; i++) {
    int lin = t + i * 256;
    int r = lin >> 6, c = lin & 63;  // r: s-offset, c: d-offset
    tile[r][c] = src[(long long)r * 1024 + c];
  }
  __syncthreads();
  unsigned short* dst = VT + ((long long)b * 1024 + d0) * 2048 + s0;
#pragma unroll
  for (int i = 0; i < 16; i++) {
    int lin = t + i * 256;
    int r = lin >> 6, c = lin & 63;  // r: d-offset, c: s-offset
    dst[(long long)r * 2048 + c] = tile[c][r];
  }
}

// ------------------------------------------------------------- row softmax
// S: [8192][2048] fp32 -> P: [8192][2048] bf16. One block per row.
__global__ __launch_bounds__(256) void softmax_rows(
    const float* __restrict__ S, unsigned short* __restrict__ P) {
  const long long row = blockIdx.x;
  const float* s = S + row * 2048;
  const int t = threadIdx.x;
  float v[8];
  float mx = -3.4e38f;
#pragma unroll
  for (int i = 0; i < 8; i++) {
    v[i] = s[t + i * 256];
    mx = fmaxf(mx, v[i]);
  }
#pragma unroll
  for (int o = 32; o >= 1; o >>= 1) mx = fmaxf(mx, __shfl_xor(mx, o));
  __shared__ float red[4], red2[4];
  if ((t & 63) == 0) red[t >> 6] = mx;
  __syncthreads();
  mx = fmaxf(fmaxf(red[0], red[1]), fmaxf(red[2], red[3]));
  float sum = 0.f;
#pragma unroll
  for (int i = 0; i < 8; i++) {
    v[i] = __expf(v[i] - mx);
    sum += v[i];
  }
#pragma unroll
  for (int o = 32; o >= 1; o >>= 1) sum += __shfl_xor(sum, o);
  if ((t & 63) == 0) red2[t >> 6] = sum;
  __syncthreads();
  sum = red2[0] + red2[1] + red2[2] + red2[3];
  const float inv = 1.0f / sum;
  unsigned short* p = P + row * 2048;
#pragma unroll
  for (int i = 0; i < 8; i++) p[t + i * 256] = f32_to_bf16(v[i] * inv);
}

// ----------------------------------------------------------------- launcher
extern "C" void kernel_launch(void* const* d_in, const int* in_sizes, int n_in,
                              void* d_out, int out_size, void* d_ws,
                              size_t ws_size, hipStream_t stream) {
  const float* x = (const float*)d_in[0];
  const float* wq = (const float*)d_in[1];
  const float* bq = (const float*)d_in[2];
  const float* wk = (const float*)d_in[3];
  const float* bk = (const float*)d_in[4];
  const float* wv = (const float*)d_in[5];
  const float* bv = (const float*)d_in[6];
  const float* wo = (const float*)d_in[7];
  const float* bo = (const float*)d_in[8];
  float* out = (float*)d_out;
  char* ws = (char*)d_ws;
  const size_t MB = 1ull << 20;

  unsigned short* xb  = (unsigned short*)(ws + 0);        // 16MB, later O
  unsigned short* wqb = (unsigned short*)(ws + 16 * MB);  // 2MB
  unsigned short* wkb = (unsigned short*)(ws + 18 * MB);
  unsigned short* wvb = (unsigned short*)(ws + 20 * MB);
  unsigned short* wob = (unsigned short*)(ws + 22 * MB);
  unsigned short* Q   = (unsigned short*)(ws + 24 * MB);  // 16MB
  unsigned short* Kb  = (unsigned short*)(ws + 40 * MB);  // 16MB
  unsigned short* VT  = (unsigned short*)(ws + 56 * MB);  // 16MB
  unsigned short* V   = (unsigned short*)(ws + 72 * MB);  // 16MB (dies at transpose)
  float*          S   = (float*)(ws + 72 * MB);           // 64MB [72,136)
  unsigned short* P   = Q;                                // 32MB over Q+K
  unsigned short* O   = xb;                               // 16MB over x

  // 1) casts to bf16
  cast_f32_bf16<<<dim3(8192), dim3(256), 0, stream>>>((const float4*)x,
                                                      (ushort4*)xb, 2097152);
  cast_f32_bf16<<<dim3(1024), dim3(256), 0, stream>>>((const float4*)wq,
                                                      (ushort4*)wqb, 262144);
  cast_f32_bf16<<<dim3(1024), dim3(256), 0, stream>>>((const float4*)wk,
                                                      (ushort4*)wkb, 262144);
  cast_f32_bf16<<<dim3(1024), dim3(256), 0, stream>>>((const float4*)wv,
                                                      (ushort4*)wvb, 262144);
  cast_f32_bf16<<<dim3(1024), dim3(256), 0, stream>>>((const float4*)wo,
                                                      (ushort4*)wob, 262144);

  // 2) Q/K/V projections: [8192,1024] = x_bf16 @ W^T + b, bf16 out
  gemm_bt<<<dim3(8, 64, 1), dim3(256), 0, stream>>>(xb, wqb, Q, bq, 8192, 1024,
                                                    1024, 1.f, 1, 0, 0, 0);
  gemm_bt<<<dim3(8, 64, 1), dim3(256), 0, stream>>>(xb, wkb, Kb, bk, 8192, 1024,
                                                    1024, 1.f, 1, 0, 0, 0);
  gemm_bt<<<dim3(8, 64, 1), dim3(256), 0, stream>>>(xb, wvb, V, bv, 8192, 1024,
                                                    1024, 1.f, 1, 0, 0, 0);

  // 3) V -> VT
  transpose_v<<<dim3(16, 32, 4), dim3(256), 0, stream>>>(V, VT);

  // 4) S = Q K^T / 32, fp32, batched over 4
  gemm_bt<<<dim3(16, 16, 4), dim3(256), 0, stream>>>(
      Q, Kb, S, nullptr, 2048, 2048, 1024, 0.03125f, 0, 2048ll * 1024,
      2048ll * 1024, 2048ll * 2048);

  // 5) P = softmax rows of S (bf16)
  softmax_rows<<<dim3(8192), dim3(256), 0, stream>>>(S, P);

  // 6) O = P @ V  (via VT, B^T form), bf16
  gemm_bt<<<dim3(8, 16, 4), dim3(256), 0, stream>>>(
      P, VT, O, nullptr, 2048, 1024, 2048, 1.f, 1, 2048ll * 2048, 1024ll * 2048,
      2048ll * 1024);

  // 7) out = O @ Wo^T + bo, fp32 to d_out
  gemm_bt<<<dim3(8, 64, 1), dim3(256), 0, stream>>>(O, wob, out, bo, 8192, 1024,
                                                    1024, 1.f, 0, 0, 0, 0);
}

// Round 2
// 342.138 us; speedup vs baseline: 1.0748x; 1.0748x over previous
//
#include <hip/hip_runtime.h>

// SelfAttention: x(4,2048,1024) fp32; Linear y = x @ W^T + b for Q,K,V;
// S = QK^T/32; P = softmax(S); O = P V; out = O @ Wo^T + bo.
// Strategy: bf16 MFMA (16x16x32) m97-style gemm_bt everywhere.
// R2: XOR-swizzled LDS layout (chunk ^= row&7) to kill the 2x bank-conflict
//     penalty on ds_read_b128 (R1: SQ_LDS_BANK_CONFLICT=1.26e7, MfmaUtil 20%).
// Workspace layout (136 MB total, aliased by lifetime):
//   [0,16)MB    x_bf16  -> later O (attn output, bf16)
//   [16,24)MB   wq,wk,wv,wo bf16 (2MB each)
//   [24,40)MB   Q bf16  -> later P (first half)
//   [40,56)MB   K bf16  -> later P (second half)   (P = [24,56) = 32MB)
//   [56,72)MB   VT bf16 (V transposed, [4][1024][2048])
//   [72,88)MB   V bf16  -> dead after transpose; S fp32 = [72,136) (64MB)

typedef __bf16 bf16x8 __attribute__((ext_vector_type(8)));
typedef float f32x4 __attribute__((ext_vector_type(4)));

__device__ __forceinline__ unsigned short f32_to_bf16(float f) {
  unsigned int u = __float_as_uint(f);
  u += 0x7fffu + ((u >> 16) & 1u);   // round-to-nearest-even
  return (unsigned short)(u >> 16);
}

__device__ __forceinline__ void load_lds16(const void* g, void* l) {
  __builtin_amdgcn_global_load_lds(
      (const __attribute__((address_space(1))) void*)g,
      (__attribute__((address_space(3))) void*)l, 16, 0, 0);
}

// ---------------------------------------------------------------- cast kernel
__global__ __launch_bounds__(256) void cast_f32_bf16(
    const float4* __restrict__ in, ushort4* __restrict__ out, int n4) {
  int i = blockIdx.x * 256 + threadIdx.x;
  if (i < n4) {
    float4 f = in[i];
    ushort4 u;
    u.x = f32_to_bf16(f.x);
    u.y = f32_to_bf16(f.y);
    u.z = f32_to_bf16(f.z);
    u.w = f32_to_bf16(f.w);
    out[i] = u;
  }
}

// ------------------------------------------------------------ gemm (B^T form)
// C[b][M][N] = alpha * A[b][M][K] * B[b][N][K]^T + bias[N]
// A,B bf16 (as ushort); C fp32 or bf16 per out_bf16 flag.
// Tile 128x128, BK=64, 256 threads = 4 waves in 2x2, each wave 64x64 = 4x4
// MFMA 16x16x32 accumulators. Staging via global_load_lds dwordx4 (m97).
// LDS layout: physical 16B chunk p of row r holds logical chunk p^(r&7).
__global__ __launch_bounds__(256) void gemm_bt(
    const unsigned short* __restrict__ A, const unsigned short* __restrict__ B,
    void* __restrict__ C, const float* __restrict__ bias,
    int M, int N, int K, float alpha, int out_bf16,
    long long sA, long long sB, long long sC) {
  __shared__ unsigned short As[128 * 64];
  __shared__ unsigned short Bs[128 * 64];

  const int bz = blockIdx.z;
  A += (long long)bz * sA;
  B += (long long)bz * sB;

  const int bm = blockIdx.y, bn = blockIdx.x;
  const int tid = threadIdx.x;
  const int lane = tid & 63, wave = tid >> 6;
  const int wr = wave >> 1, wc = wave & 1;
  const int l16 = lane & 15, quad = lane >> 4;

  f32x4 acc[4][4] = {};

  // staging map: thread t covers global row (t>>3)+32r; its LDS physical
  // chunk is (t&7), so it must fetch logical (global) chunk (t&7)^(row&7).
  const int srow = tid >> 3;
  const int xr = srow & 7;                       // row&7 (stable mod 32-row steps)
  const int scol = ((tid & 7) ^ xr) * 8;         // swizzled global chunk, elems
  const unsigned short* gA = A + (long long)(bm * 128 + srow) * K + scol;
  const unsigned short* gB = B + (long long)(bn * 128 + srow) * K + scol;
  char* ldsA = (char*)As + wave * 1024;  // wave-uniform base; HW adds lane*16
  char* ldsB = (char*)Bs + wave * 1024;

  for (int k0 = 0; k0 < K; k0 += 64) {
#pragma unroll
    for (int r = 0; r < 4; r++)
      load_lds16(gA + k0 + (long long)r * 32 * K, ldsA + r * 4096);
#pragma unroll
    for (int r = 0; r < 4; r++)
      load_lds16(gB + k0 + (long long)r * 32 * K, ldsB + r * 4096);
    __syncthreads();  // drains vmcnt: LDS tiles ready

    const int swz = l16 & 7;  // (row&7) for every fragment row this lane reads
#pragma unroll
    for (int kk = 0; kk < 64; kk += 32) {
      bf16x8 af[4], bf[4];
      const int lc = (kk >> 3) + quad;           // logical chunk 0..7
      const int pco = (lc ^ swz) * 8;            // physical chunk offset, elems
#pragma unroll
      for (int mi = 0; mi < 4; mi++)
        af[mi] = *(const bf16x8*)(As + (wr * 64 + mi * 16 + l16) * 64 + pco);
#pragma unroll
      for (int ni = 0; ni < 4; ni++)
        bf[ni] = *(const bf16x8*)(Bs + (wc * 64 + ni * 16 + l16) * 64 + pco);
#pragma unroll
      for (int mi = 0; mi < 4; mi++)
#pragma unroll
        for (int ni = 0; ni < 4; ni++)
          acc[mi][ni] = __builtin_amdgcn_mfma_f32_16x16x32_bf16(
              af[mi], bf[ni], acc[mi][ni], 0, 0, 0);
    }
    __syncthreads();  // protect LDS before next stage overwrites
  }

  // epilogue: D element (row = quad*4+reg, col = l16) within each 16x16 tile
  const int orow0 = bm * 128 + wr * 64 + quad * 4;
  const int ocol0 = bn * 128 + wc * 64 + l16;
  if (out_bf16) {
    unsigned short* Cp = (unsigned short*)C + (long long)bz * sC;
#pragma unroll
    for (int mi = 0; mi < 4; mi++)
#pragma unroll
      for (int ni = 0; ni < 4; ni++) {
        const int col = ocol0 + ni * 16;
        const float bv = bias ? bias[col] : 0.f;
#pragma unroll
        for (int r = 0; r < 4; r++) {
          const float o = acc[mi][ni][r] * alpha + bv;
          Cp[(long long)(orow0 + mi * 16 + r) * N + col] = f32_to_bf16(o);
        }
      }
  } else {
    float* Cp = (float*)C + (long long)bz * sC;
#pragma unroll
    for (int mi = 0; mi < 4; mi++)
#pragma unroll
      for (int ni = 0; ni < 4; ni++) {
        const int col = ocol0 + ni * 16;
        const float bv = bias ? bias[col] : 0.f;
#pragma unroll
        for (int r = 0; r < 4; r++) {
          const float o = acc[mi][ni][r] * alpha + bv;
          Cp[(long long)(orow0 + mi * 16 + r) * N + col] = o;
        }
      }
  }
}

// ------------------------------------------------------- V transpose (bf16)
// V: [4*2048][1024] -> VT: [4][1024][2048]
__global__ __launch_bounds__(256) void transpose_v(
    const unsigned short* __restrict__ V, unsigned short* __restrict__ VT) {
  __shared__ unsigned short tile[64][65];
  const int d0 = blockIdx.x * 64, s0 = blockIdx.y * 64, b = blockIdx.z;
  const int t = threadIdx.x;
  const unsigned short* src = V + ((long long)b * 2048 + s0) * 1024 + d0;
#pragma unroll
  for (int i = 0; i < 16; i++) {
    int lin = t + i * 256;
    int r = lin >> 6, c = lin & 63;  // r: s-offset, c: d-offset
    tile[r][c] = src[(long long)r * 1024 + c];
  }
  __syncthreads();
  unsigned short* dst = VT + ((long long)b * 1024 + d0) * 2048 + s0;
#pragma unroll
  for (int i = 0; i < 16; i++) {
    int lin = t + i * 256;
    int r = lin >> 6, c = lin & 63;  // r: d-offset, c: s-offset
    dst[(long long)r * 2048 + c] = tile[c][r];
  }
}

// ------------------------------------------------------------- row softmax
// S: [8192][2048] fp32 -> P: [8192][2048] bf16. One block per row.
__global__ __launch_bounds__(256) void softmax_rows(
    const float* __restrict__ S, unsigned short* __restrict__ P) {
  const long long row = blockIdx.x;
  const float* s = S + row * 2048;
  const int t = threadIdx.x;
  float v[8];
  float mx = -3.4e38f;
#pragma unroll
  for (int i = 0; i < 8; i++) {
    v[i] = s[t + i * 256];
    mx = fmaxf(mx, v[i]);
  }
#pragma unroll
  for (int o = 32; o >= 1; o >>= 1) mx = fmaxf(mx, __shfl_xor(mx, o));
  __shared__ float red[4], red2[4];
  if ((t & 63) == 0) red[t >> 6] = mx;
  __syncthreads();
  mx = fmaxf(fmaxf(red[0], red[1]), fmaxf(red[2], red[3]));
  float sum = 0.f;
#pragma unroll
  for (int i = 0; i < 8; i++) {
    v[i] = __expf(v[i] - mx);
    sum += v[i];
  }
#pragma unroll
  for (int o = 32; o >= 1; o >>= 1) sum += __shfl_xor(sum, o);
  if ((t & 63) == 0) red2[t >> 6] = sum;
  __syncthreads();
  sum = red2[0] + red2[1] + red2[2] + red2[3];
  const float inv = 1.0f / sum;
  unsigned short* p = P + row * 2048;
#pragma unroll
  for (int i = 0; i < 8; i++) p[t + i * 256] = f32_to_bf16(v[i] * inv);
}

// ----------------------------------------------------------------- launcher
extern "C" void kernel_launch(void* const* d_in, const int* in_sizes, int n_in,
                              void* d_out, int out_size, void* d_ws,
                              size_t ws_size, hipStream_t stream) {
  const float* x = (const float*)d_in[0];
  const float* wq = (const float*)d_in[1];
  const float* bq = (const float*)d_in[2];
  const float* wk = (const float*)d_in[3];
  const float* bk = (const float*)d_in[4];
  const float* wv = (const float*)d_in[5];
  const float* bv = (const float*)d_in[6];
  const float* wo = (const float*)d_in[7];
  const float* bo = (const float*)d_in[8];
  float* out = (float*)d_out;
  char* ws = (char*)d_ws;
  const size_t MB = 1ull << 20;

  unsigned short* xb  = (unsigned short*)(ws + 0);        // 16MB, later O
  unsigned short* wqb = (unsigned short*)(ws + 16 * MB);  // 2MB
  unsigned short* wkb = (unsigned short*)(ws + 18 * MB);
  unsigned short* wvb = (unsigned short*)(ws + 20 * MB);
  unsigned short* wob = (unsigned short*)(ws + 22 * MB);
  unsigned short* Q   = (unsigned short*)(ws + 24 * MB);  // 16MB
  unsigned short* Kb  = (unsigned short*)(ws + 40 * MB);  // 16MB
  unsigned short* VT  = (unsigned short*)(ws + 56 * MB);  // 16MB
  unsigned short* V   = (unsigned short*)(ws + 72 * MB);  // 16MB (dies at transpose)
  float*          S   = (float*)(ws + 72 * MB);           // 64MB [72,136)
  unsigned short* P   = Q;                                // 32MB over Q+K
  unsigned short* O   = xb;                               // 16MB over x

  // 1) casts to bf16
  cast_f32_bf16<<<dim3(8192), dim3(256), 0, stream>>>((const float4*)x,
                                                      (ushort4*)xb, 2097152);
  cast_f32_bf16<<<dim3(1024), dim3(256), 0, stream>>>((const float4*)wq,
                                                      (ushort4*)wqb, 262144);
  cast_f32_bf16<<<dim3(1024), dim3(256), 0, stream>>>((const float4*)wk,
                                                      (ushort4*)wkb, 262144);
  cast_f32_bf16<<<dim3(1024), dim3(256), 0, stream>>>((const float4*)wv,
                                                      (ushort4*)wvb, 262144);
  cast_f32_bf16<<<dim3(1024), dim3(256), 0, stream>>>((const float4*)wo,
                                                      (ushort4*)wob, 262144);

  // 2) Q/K/V projections: [8192,1024] = x_bf16 @ W^T + b, bf16 out
  gemm_bt<<<dim3(8, 64, 1), dim3(256), 0, stream>>>(xb, wqb, Q, bq, 8192, 1024,
                                                    1024, 1.f, 1, 0, 0, 0);
  gemm_bt<<<dim3(8, 64, 1), dim3(256), 0, stream>>>(xb, wkb, Kb, bk, 8192, 1024,
                                                    1024, 1.f, 1, 0, 0, 0);
  gemm_bt<<<dim3(8, 64, 1), dim3(256), 0, stream>>>(xb, wvb, V, bv, 8192, 1024,
                                                    1024, 1.f, 1, 0, 0, 0);

  // 3) V -> VT
  transpose_v<<<dim3(16, 32, 4), dim3(256), 0, stream>>>(V, VT);

  // 4) S = Q K^T / 32, fp32, batched over 4
  gemm_bt<<<dim3(16, 16, 4), dim3(256), 0, stream>>>(
      Q, Kb, S, nullptr, 2048, 2048, 1024, 0.03125f, 0, 2048ll * 1024,
      2048ll * 1024, 2048ll * 2048);

  // 5) P = softmax rows of S (bf16)
  softmax_rows<<<dim3(8192), dim3(256), 0, stream>>>(S, P);

  // 6) O = P @ V  (via VT, B^T form), bf16
  gemm_bt<<<dim3(8, 16, 4), dim3(256), 0, stream>>>(
      P, VT, O, nullptr, 2048, 1024, 2048, 1.f, 1, 2048ll * 2048, 1024ll * 2048,
      2048ll * 1024);

  // 7) out = O @ Wo^T + bo, fp32 to d_out
  gemm_bt<<<dim3(8, 64, 1), dim3(256), 0, stream>>>(O, wob, out, bo, 8192, 1024,
                                                    1024, 1.f, 0, 0, 0, 0);
}